// Round 1
// baseline (239.613 us; speedup 1.0000x reference)
//
#include <hip/hip_runtime.h>

// Affinity propagation (spatial), fused single kernel.
// guidance: [16, 8, 512, 512] f32, blur_depth: [16, 1, 512, 512] f32
// out: [16, 1, 512, 512] f32
//
// Per block: 32x32 output tile, 4 propagation iterations fully in LDS.
// Halo after 4 iters = 4 px -> blur loaded on 40x40, gates/base on 38x38.

#define TILE 32
#define G    40   // TILE + 8 (result buffer incl. halo)
#define GM   38   // TILE + 6 (gate/base region)
#define NTHREADS 512

__launch_bounds__(NTHREADS)
__global__ void affprop_kernel(const float* __restrict__ guidance,
                               const float* __restrict__ blur,
                               float* __restrict__ out) {
    __shared__ float sGate[8][GM * GM];  // 46208 B
    __shared__ float sBase[GM * GM];     //  5776 B
    __shared__ float sA[G * G];          //  6400 B
    __shared__ float sB[G * G];          //  6400 B  -> total 64784 B

    const int tid = threadIdx.x;
    const int bx0 = blockIdx.x * TILE;
    const int by0 = blockIdx.y * TILE;
    const int b   = blockIdx.z;

    const long plane = 512L * 512L;
    const float* __restrict__ blurB = blur + (long)b * plane;
    const float* __restrict__ guidB = guidance + (long)b * 8 * plane;
    float* __restrict__ outB = out + (long)b * plane;

    // ---- Phase 1: load result_0 (blur) with zero padding into sA (G x G)
    for (int i = tid; i < G * G; i += NTHREADS) {
        int y = i / G, x = i % G;
        int gy = by0 - 4 + y, gx = bx0 - 4 + x;
        float v = 0.f;
        if ((unsigned)gy < 512u && (unsigned)gx < 512u)
            v = blurB[gy * 512 + gx];
        sA[i] = v;
    }
    __syncthreads();

    // ---- Phase 2: normalized gates + base = (1-gate_sum)*raw on GM x GM
    // buffer coords y,x in [1, 39); gate index i = (y-1)*GM + (x-1)
    for (int i = tid; i < GM * GM; i += NTHREADS) {
        int y = i / GM + 1, x = i % GM + 1;
        int gy = by0 - 4 + y, gx = bx0 - 4 + x;
        if ((unsigned)gy < 512u && (unsigned)gx < 512u) {
            // OFFSETS: k -> (di, dj); shifted[i,j] = src[i+di, j+dj]
            const int di[8] = {1, 1, 1, 0, 0, -1, -1, -1};
            const int dj[8] = {1, 0, -1, 1, -1, 1, 0, -1};
            float g[8];
            float aw = 0.f;
            #pragma unroll
            for (int k = 0; k < 8; ++k) {
                int yy = gy + di[k], xx = gx + dj[k];
                float v = 0.f;
                if ((unsigned)yy < 512u && (unsigned)xx < 512u)
                    v = guidB[k * plane + yy * 512 + xx];
                g[k] = v;
                aw += fabsf(v);
            }
            float r = (aw > 0.f) ? (1.0f / aw) : 0.f;
            float gs = 0.f;
            #pragma unroll
            for (int k = 0; k < 8; ++k) {
                float w = g[k] * r;
                sGate[k][i] = w;
                gs += w;
            }
            sBase[i] = (1.0f - gs) * sA[y * G + x];
        } else {
            // Outside the global image: everything stays exactly zero.
            #pragma unroll
            for (int k = 0; k < 8; ++k) sGate[k][i] = 0.f;
            sBase[i] = 0.f;
        }
    }
    __syncthreads();

    // ---- Phase 3: 4 propagation iterations, shrinking regions, LDS dbuf
    float* src = sA;
    float* dst = sB;
    #pragma unroll
    for (int t = 1; t <= 4; ++t) {
        const int m = t;            // margin in buffer coords
        const int w = G - 2 * m;    // region width: 38, 36, 34, 32
        const int n = w * w;
        for (int i = tid; i < n; i += NTHREADS) {
            int y = i / w + m, x = i % w + m;
            int gi = (y - 1) * GM + (x - 1);
            float acc = sBase[gi];
            acc += sGate[0][gi] * src[(y + 1) * G + (x + 1)];
            acc += sGate[1][gi] * src[(y + 1) * G + (x    )];
            acc += sGate[2][gi] * src[(y + 1) * G + (x - 1)];
            acc += sGate[3][gi] * src[(y    ) * G + (x + 1)];
            acc += sGate[4][gi] * src[(y    ) * G + (x - 1)];
            acc += sGate[5][gi] * src[(y - 1) * G + (x + 1)];
            acc += sGate[6][gi] * src[(y - 1) * G + (x    )];
            acc += sGate[7][gi] * src[(y - 1) * G + (x - 1)];
            dst[y * G + x] = acc;
        }
        __syncthreads();
        float* tmp = src; src = dst; dst = tmp;
    }

    // After 4 iterations + 4 swaps, final result is in src (= sA), region [4,36)
    for (int i = tid; i < TILE * TILE; i += NTHREADS) {
        int y = i / TILE + 4, x = i % TILE + 4;
        int gy = by0 - 4 + y, gx = bx0 - 4 + x;  // always in-bounds
        outB[gy * 512 + gx] = src[y * G + x];
    }
}

extern "C" void kernel_launch(void* const* d_in, const int* in_sizes, int n_in,
                              void* d_out, int out_size, void* d_ws, size_t ws_size,
                              hipStream_t stream) {
    const float* guidance = (const float*)d_in[0];
    const float* blur     = (const float*)d_in[1];
    float* out            = (float*)d_out;

    dim3 grid(512 / TILE, 512 / TILE, 16);  // 16 x 16 tiles x 16 batch
    affprop_kernel<<<grid, NTHREADS, 0, stream>>>(guidance, blur, out);
}

// Round 2
// 218.418 us; speedup vs baseline: 1.0970x; 1.0970x over previous
//
#include <hip/hip_runtime.h>

// Affinity propagation (spatial), fused single kernel, round 2:
// gates + base live in REGISTERS (each thread statically owns <=3 of the
// 38x38 gate points); only the propagating result field lives in LDS.
//
// guidance: [16, 8, 512, 512] f32, blur_depth: [16, 1, 512, 512] f32
// out: [16, 1, 512, 512] f32

#define TILE 32
#define G    40            // result buffer side (TILE + 2*4 halo)
#define GM   38            // gate/base region side (TILE + 2*3)
#define NPTS (GM * GM)     // 1444
#define NTHREADS 512
#define PPT 3              // ceil(1444 / 512)

__launch_bounds__(NTHREADS)
__global__ void affprop_kernel(const float* __restrict__ guidance,
                               const float* __restrict__ blur,
                               float* __restrict__ out) {
    __shared__ float sA[G * G];   // 6400 B
    __shared__ float sB[G * G];   // 6400 B   -> 12.8 KB total

    const int tid = threadIdx.x;
    const int bx0 = blockIdx.x * TILE;
    const int by0 = blockIdx.y * TILE;
    const int b   = blockIdx.z;

    const long plane = 512L * 512L;
    const float* __restrict__ blurB = blur + (long)b * plane;
    const float* __restrict__ guidB = guidance + (long)b * 8 * plane;
    float* __restrict__ outB = out + (long)b * plane;

    // ---- Phase 1: result_0 (blur) with zero padding into sA (G x G)
    for (int i = tid; i < G * G; i += NTHREADS) {
        int y = i / G, x = i % G;
        int gy = by0 - 4 + y, gx = bx0 - 4 + x;
        float v = 0.f;
        if ((unsigned)gy < 512u && (unsigned)gx < 512u)
            v = blurB[gy * 512 + gx];
        sA[i] = v;
    }
    __syncthreads();

    // ---- Phase 2: per-thread gates/base into registers.
    // Gate point i: buffer coords y = i/GM + 1, x = i%GM + 1 (y,x in [1,39)).
    float ga[PPT][8];
    float gbase[PPT];
    int   gaddr[PPT];   // LDS word index of (y-1, x-1) — all 8 neighbor
                        // offsets and the write slot are non-negative consts
    int   gmsk[PPT];    // bit t-1 set <=> point inside iteration-t region

    const int di[8] = {1, 1, 1, 0, 0, -1, -1, -1};
    const int dj[8] = {1, 0, -1, 1, -1, 1, 0, -1};

    #pragma unroll
    for (int p = 0; p < PPT; ++p) {
        #pragma unroll
        for (int k = 0; k < 8; ++k) ga[p][k] = 0.f;
        gbase[p] = 0.f;
        gaddr[p] = 0;
        gmsk[p]  = 0;

        int i = tid + p * NTHREADS;
        if (i < NPTS) {
            int y = i / GM + 1, x = i % GM + 1;
            gaddr[p] = (y - 1) * G + (x - 1);
            int m = 0;
            #pragma unroll
            for (int t = 1; t <= 4; ++t)
                if (y >= t && y < G - t && x >= t && x < G - t) m |= 1 << (t - 1);
            gmsk[p] = m;

            int gy = by0 - 4 + y, gx = bx0 - 4 + x;
            if ((unsigned)gy < 512u && (unsigned)gx < 512u) {
                float g[8];
                float aw = 0.f;
                #pragma unroll
                for (int k = 0; k < 8; ++k) {
                    int yy = gy + di[k], xx = gx + dj[k];
                    float v = 0.f;
                    if ((unsigned)yy < 512u && (unsigned)xx < 512u)
                        v = guidB[k * plane + yy * 512 + xx];
                    g[k] = v;
                    aw += fabsf(v);
                }
                float r = (aw > 0.f) ? (1.0f / aw) : 0.f;
                float gs = 0.f;
                #pragma unroll
                for (int k = 0; k < 8; ++k) {
                    float wv = g[k] * r;
                    ga[p][k] = wv;
                    gs += wv;
                }
                gbase[p] = (1.0f - gs) * sA[y * G + x];
            }
            // out-of-image: gates/base stay 0 -> point writes exact 0 each
            // iteration, preserving the zero-padding invariant.
        }
    }
    // No barrier needed: iteration 1 writes only sB, reads only sA.

    // ---- Phase 3: 4 propagation iterations, LDS double-buffer.
    float* src = sA;
    float* dst = sB;
    #pragma unroll
    for (int t = 1; t <= 4; ++t) {
        #pragma unroll
        for (int p = 0; p < PPT; ++p) {
            if (gmsk[p] & (1 << (t - 1))) {
                const float* s = src + gaddr[p];
                float acc = gbase[p];
                acc += ga[p][7] * s[0];             // (-1,-1)
                acc += ga[p][6] * s[1];             // (-1, 0)
                acc += ga[p][5] * s[2];             // (-1,+1)
                acc += ga[p][4] * s[G];             // ( 0,-1)
                acc += ga[p][3] * s[G + 2];         // ( 0,+1)
                acc += ga[p][2] * s[2 * G];         // (+1,-1)
                acc += ga[p][1] * s[2 * G + 1];     // (+1, 0)
                acc += ga[p][0] * s[2 * G + 2];     // (+1,+1)
                dst[gaddr[p] + (G + 1)] = acc;
            }
        }
        __syncthreads();
        float* tmp = src; src = dst; dst = tmp;
    }

    // After 4 iterations + swaps, final result is in src (= sA), region [4,36)
    for (int i = tid; i < TILE * TILE; i += NTHREADS) {
        int y = i / TILE + 4, x = i % TILE + 4;
        outB[(by0 - 4 + y) * 512 + (bx0 - 4 + x)] = src[y * G + x];
    }
}

extern "C" void kernel_launch(void* const* d_in, const int* in_sizes, int n_in,
                              void* d_out, int out_size, void* d_ws, size_t ws_size,
                              hipStream_t stream) {
    const float* guidance = (const float*)d_in[0];
    const float* blur     = (const float*)d_in[1];
    float* out            = (float*)d_out;

    dim3 grid(512 / TILE, 512 / TILE, 16);  // 16 x 16 tiles x 16 batch
    affprop_kernel<<<grid, NTHREADS, 0, stream>>>(guidance, blur, out);
}